// Round 6
// baseline (364.498 us; speedup 1.0000x reference)
//
#include <hip/hip_runtime.h>
#include <math.h>

typedef unsigned short u16;
typedef unsigned int   u32;
typedef __attribute__((ext_vector_type(4))) float f32x4;
typedef __attribute__((ext_vector_type(8))) short s16x8;
typedef __attribute__((ext_vector_type(4))) unsigned short u16x4;

#define B_N   2
#define S_N   2048
#define HID_N 1024
#define H_N   8
#define HKV_N 2
#define D_N   256
#define QKVW  5120   // qkv_raw row width: 2048 q | 2048 gate | 512 k | 512 v

__device__ __forceinline__ u16 f2bf(float f) {
  union { float f; u32 u; } x; x.f = f;
  u32 r = x.u + 0x7FFFu + ((x.u >> 16) & 1u);
  return (u16)(r >> 16);
}
__device__ __forceinline__ float bf2f(u16 u) {
  union { u32 u; float f; } x; x.u = ((u32)u) << 16; return x.f;
}
__device__ __forceinline__ u32 pk_bf16(float lo, float hi) {
  u32 r;
  asm("v_cvt_pk_bf16_f32 %0, %1, %2" : "=v"(r) : "v"(lo), "v"(hi));
  return r;
}
__device__ __forceinline__ void gload_lds16(const u16* g, u16* l) {
  __builtin_amdgcn_global_load_lds((const __attribute__((address_space(1))) u32*)g,
                                   (__attribute__((address_space(3))) u32*)l, 16, 0, 0);
}

// ---------------- fp32 -> bf16 cast ----------------
__global__ __launch_bounds__(256)
void cast_bf16_kernel(const float* __restrict__ src, u16* __restrict__ dst, int n4) {
  int i = blockIdx.x * blockDim.x + threadIdx.x;
  int stride = gridDim.x * blockDim.x;
  for (; i < n4; i += stride) {
    float4 v = reinterpret_cast<const float4*>(src)[i];
    u16x4 o;
    o.x = f2bf(v.x); o.y = f2bf(v.y); o.z = f2bf(v.z); o.w = f2bf(v.w);
    reinterpret_cast<u16x4*>(dst)[i] = o;
  }
}

// ---------------- RoPE trig table ----------------
__global__ __launch_bounds__(256)
void trig_kernel(const int* __restrict__ pos, float* __restrict__ ct, float* __restrict__ st) {
  int i = blockIdx.x * blockDim.x + threadIdx.x;
  if (i >= S_N * 32) return;
  int s = i >> 5, j = i & 31;
  double inv = exp(-(double)j * (log(1.0e7) / 32.0));
  double ang = (double)pos[s] * inv;
  ct[i] = (float)cos(ang);
  st[i] = (float)sin(ang);
}

// ---------------- bf16 GEMM: C[M,N] = A[M,K] @ Bw[N,K]^T ----------------
template <int OUT_BF16>
__global__ __launch_bounds__(256, 2)
void gemm_bt_kernel(const u16* __restrict__ A, const u16* __restrict__ Bw,
                    void* __restrict__ Cout, int M, int N, int K) {
  const int nbn = N >> 7;
  const int bm = blockIdx.x / nbn;
  const int bn = blockIdx.x % nbn;
  const int tid = threadIdx.x;
  const int lane = tid & 63;
  const int wr = tid >> 7;
  const int wc = (tid >> 6) & 1;
  __shared__ u16 sA[2][128 * 32];
  __shared__ u16 sB[2][128 * 32];
  f32x4 acc[4][4] = {};
  const u16* Ab = A + (size_t)(bm << 7) * K;
  const u16* Bb = Bw + (size_t)(bn << 7) * K;
  const int r_st = tid >> 2;
  const int c_st = (tid & 3) * 8;
  const int nkt = K >> 5;

  auto stage = [&](int buf, int kt) {
    const int k0 = kt << 5;
    gload_lds16(Ab + (size_t)r_st * K + k0 + c_st,        &sA[buf][tid * 8]);
    gload_lds16(Ab + (size_t)(r_st + 64) * K + k0 + c_st, &sA[buf][2048 + tid * 8]);
    gload_lds16(Bb + (size_t)r_st * K + k0 + c_st,        &sB[buf][tid * 8]);
    gload_lds16(Bb + (size_t)(r_st + 64) * K + k0 + c_st, &sB[buf][2048 + tid * 8]);
  };

  stage(0, 0);
  int cur = 0;
  const int ra = (wr << 6) + (lane & 15);
  const int rb = (wc << 6) + (lane & 15);
  const int ks = (lane >> 4) << 3;
  for (int kt = 0; kt < nkt; ++kt) {
    asm volatile("s_waitcnt vmcnt(0)" ::: "memory");
    __syncthreads();
    if (kt + 1 < nkt) stage(cur ^ 1, kt + 1);
    const u16* sa = sA[cur];
    const u16* sb = sB[cur];
    s16x8 af[4], bfr[4];
#pragma unroll
    for (int m = 0; m < 4; ++m) af[m] = *reinterpret_cast<const s16x8*>(sa + (ra + m * 16) * 32 + ks);
#pragma unroll
    for (int n = 0; n < 4; ++n) bfr[n] = *reinterpret_cast<const s16x8*>(sb + (rb + n * 16) * 32 + ks);
#pragma unroll
    for (int m = 0; m < 4; ++m)
#pragma unroll
      for (int n = 0; n < 4; ++n)
        acc[m][n] = __builtin_amdgcn_mfma_f32_16x16x32_bf16(af[m], bfr[n], acc[m][n], 0, 0, 0);
    cur ^= 1;
  }
  const int row0 = (bm << 7) + (wr << 6) + ((lane >> 4) << 2);
  const int col0 = (bn << 7) + (wc << 6) + (lane & 15);
#pragma unroll
  for (int m = 0; m < 4; ++m)
#pragma unroll
    for (int n = 0; n < 4; ++n)
#pragma unroll
      for (int j = 0; j < 4; ++j) {
        size_t idx = (size_t)(row0 + m * 16 + j) * N + col0 + n * 16;
        if (OUT_BF16) ((u16*)Cout)[idx] = f2bf(acc[m][n][j]);
        else          ((float*)Cout)[idx] = acc[m][n][j];
      }
}

// ---------------- RMSNorm + RoPE for q and k ----------------
__global__ __launch_bounds__(256)
void normrope_kernel(const u16* __restrict__ qkv, const float* __restrict__ qw,
                     const float* __restrict__ kw, const float* __restrict__ ct,
                     const float* __restrict__ st, u16* __restrict__ q_r,
                     u16* __restrict__ k_r) {
  const int lane = threadIdx.x & 63;
  const int row = blockIdx.x * 4 + (threadIdx.x >> 6);
  const int nq = B_N * S_N * H_N;
  const u16* src; u16* dst; const float* w;
  int s;
  if (row < nq) {
    int h = row & 7; int bs = row >> 3; s = bs & (S_N - 1); int b = bs >> 11;
    src = qkv + (size_t)(b * S_N + s) * QKVW + h * 256;
    dst = q_r + ((size_t)(b * H_N + h) * S_N + s) * 256;
    w = qw;
  } else {
    int r2 = row - nq;
    int h = r2 & 1; int bs = r2 >> 1; s = bs & (S_N - 1); int b = bs >> 11;
    src = qkv + (size_t)(b * S_N + s) * QKVW + 4096 + h * 256;
    dst = k_r + ((size_t)(b * HKV_N + h) * S_N + s) * 256;
    w = kw;
  }
  u16x4 xv = *reinterpret_cast<const u16x4*>(src + lane * 4);
  float x0 = bf2f(xv.x), x1 = bf2f(xv.y), x2 = bf2f(xv.z), x3 = bf2f(xv.w);
  float ss = x0 * x0 + x1 * x1 + x2 * x2 + x3 * x3;
#pragma unroll
  for (int off = 1; off < 64; off <<= 1) ss += __shfl_xor(ss, off);
  float rinv = rsqrtf(ss * (1.0f / 256.0f) + 1e-6f);
  float4 wv = *reinterpret_cast<const float4*>(w + lane * 4);
  float y[4] = { x0 * rinv * wv.x, x1 * rinv * wv.y, x2 * rinv * wv.z, x3 * rinv * wv.w };
  float p[4];
  p[0] = __shfl_xor(y[0], 8);
  p[1] = __shfl_xor(y[1], 8);
  p[2] = __shfl_xor(y[2], 8);
  p[3] = __shfl_xor(y[3], 8);
  if (lane < 16) {
    const float sgn = (lane < 8) ? -1.0f : 1.0f;
    const int jb = (lane * 4) & 31;
#pragma unroll
    for (int e = 0; e < 4; ++e) {
      float c = ct[(size_t)s * 32 + jb + e];
      float sn = st[(size_t)s * 32 + jb + e];
      y[e] = y[e] * c + sgn * p[e] * sn;
    }
  }
  u16x4 ov;
  ov.x = f2bf(y[0]); ov.y = f2bf(y[1]); ov.z = f2bf(y[2]); ov.w = f2bf(y[3]);
  *reinterpret_cast<u16x4*>(dst + lane * 4) = ov;
}

// ---------------- V transpose ----------------
__global__ __launch_bounds__(256)
void vtrans_kernel(const u16* __restrict__ qkv, u16* __restrict__ vt) {
  const int bid = blockIdx.x;            // 512
  const int dt = bid & 3;
  const int stile = (bid >> 2) & 31;
  const int bh = bid >> 7;
  const int b = bh >> 1, kvh = bh & 1;
  __shared__ u16 tile[64][68];
  const int t = threadIdx.x;
  const u16* src = qkv + (size_t)(b * S_N + stile * 64) * QKVW + 4608 + kvh * 256 + dt * 64;
#pragma unroll
  for (int i = 0; i < 2; ++i) {
    int sl = i * 32 + (t >> 3);
    int d8 = (t & 7) * 8;
    s16x8 v = *reinterpret_cast<const s16x8*>(src + (size_t)sl * QKVW + d8);
    u16x4 lo = { (u16)v[0], (u16)v[1], (u16)v[2], (u16)v[3] };
    u16x4 hi = { (u16)v[4], (u16)v[5], (u16)v[6], (u16)v[7] };
    *reinterpret_cast<u16x4*>(&tile[sl][d8]) = lo;
    *reinterpret_cast<u16x4*>(&tile[sl][d8 + 4]) = hi;
  }
  __syncthreads();
#pragma unroll
  for (int i = 0; i < 2; ++i) {
    int dl = i * 32 + (t >> 3);
    int s8 = (t & 7) * 8;
    u16 tmp[8];
#pragma unroll
    for (int e = 0; e < 8; ++e) tmp[e] = tile[s8 + e][dl];
    u16x4 lo = { tmp[0], tmp[1], tmp[2], tmp[3] };
    u16x4 hi = { tmp[4], tmp[5], tmp[6], tmp[7] };
    u16* dstp = vt + ((size_t)(bh * 256 + dt * 64 + dl)) * S_N + stile * 64 + s8;
    *reinterpret_cast<u16x4*>(dstp) = lo;
    *reinterpret_cast<u16x4*>(dstp + 4) = hi;
  }
}

// ---------------- flash attention + silu gating ----------------
// 4 waves (256 thr); wave owns 32 q rows of ONE head (block = GQA group of a
// 32-row q-tile); KVBLK=64; single-buffered K+V+P = exactly 80KB LDS ->
// 2 blocks/CU (2 waves/SIMD; cross-block TLP hides stage drain).
// Swapped QK^T + in-register softmax; kf/vf each read once, shared by both
// 16-row groups -> LDS bytes per q-row halved vs 16q/wave.
__global__ __launch_bounds__(256, 2)
void attn_kernel(const u16* __restrict__ q_r, const u16* __restrict__ k_r,
                 const u16* __restrict__ vt, const u16* __restrict__ qkv,
                 u16* __restrict__ act) {
  // XCD-aware remap: 2 XCDs per (b,kvh); K/V (2MB) fits per-XCD L2.
  const int dd = blockIdx.x;             // 0..255
  const int xcd = dd & 7;
  const int idx = dd >> 3;               // 0..31
  const int combo = xcd >> 1;            // b*2+kvh
  const int qt = (xcd & 1) * 32 + idx;   // 0..63
  const int b = combo >> 1;
  const int kvh = combo & 1;

  const int tid = threadIdx.x;
  const int lane = tid & 63;
  const int wv = tid >> 6;               // 0..3 -> head within GQA group
  const int h = kvh * 4 + wv;
  const int l15 = lane & 15;
  const int l4 = lane >> 4;

  __shared__ u16 sK[64 * 256];           // [kv][d], swizzled 16B slots (32KB)
  __shared__ u16 sVt[256 * 64];          // [d][kv], swizzled (32KB)
  __shared__ u16 sP[4][32 * 64];         // per-wave P, swizzled 8B slots (16KB)

  const int q0 = qt * 32;
  const u16* qb = q_r + ((size_t)(b * H_N + h) * S_N + q0) * 256;
  s16x8 qf[2][8];
#pragma unroll
  for (int rg = 0; rg < 2; ++rg)
#pragma unroll
    for (int kk = 0; kk < 8; ++kk)
      qf[rg][kk] = *reinterpret_cast<const s16x8*>(
          qb + (size_t)(rg * 16 + l15) * 256 + kk * 32 + l4 * 8);

  f32x4 oacc[2][16] = {};
  float mrow[2] = { -1e30f, -1e30f };
  float lrow[2] = { 0.f, 0.f };

  const u16* kbase = k_r + ((size_t)(b * HKV_N + kvh) * S_N) * 256;
  const u16* vbase = vt + ((size_t)(b * HKV_N + kvh) * 256) * S_N;

  // staging (256 thr): 8 x 16B each for K and V
  const int k_rb = tid >> 5;             // 0..7
  const int k_sc = tid & 31;
  const int v_rb = (tid >> 3) & 7;
  const int v_sc = tid & 7;

  auto stageKV = [&](int step) {
    const int kv0 = step << 6;
#pragma unroll
    for (int i = 0; i < 8; ++i) {
      const int row = i * 8 + k_rb;      // 0..63 ; row&7 == k_rb
      gload_lds16(kbase + (size_t)(kv0 + row) * 256 + ((k_sc ^ k_rb) << 3),
                  &sK[i * 2048 + tid * 8]);
    }
#pragma unroll
    for (int i = 0; i < 8; ++i) {
      const int rowd = i * 32 + (tid >> 3);  // 0..255 ; rowd&7 == v_rb
      gload_lds16(vbase + (size_t)rowd * S_N + kv0 + ((v_sc ^ v_rb) << 3),
                  &sVt[i * 2048 + tid * 8]);
    }
  };

  stageKV(0);
  asm volatile("s_waitcnt vmcnt(0)" ::: "memory");
  __syncthreads();

  const float scale = 0.0625f;  // 1/sqrt(256)
  const int sw = l15 & 7;
  const int swp = l15 & 14;              // even XOR for 8B P slots
  for (int step = 0; step < 32; ++step) {
    // swapped QK^T: sacc[rg][g] = S^T; lane q-col = l15 (row rg*16+l15),
    // kv = g*16 + l4*4 + j ; kf shared across both rg
    f32x4 sacc[2][4] = {};
    __builtin_amdgcn_s_setprio(1);
#pragma unroll
    for (int kk = 0; kk < 8; ++kk) {
      const int slot = kk * 4 + l4;
#pragma unroll
      for (int g = 0; g < 4; ++g) {
        s16x8 kf = *reinterpret_cast<const s16x8*>(
            sK + (g * 16 + l15) * 256 + ((slot ^ sw) << 3));
        sacc[0][g] = __builtin_amdgcn_mfma_f32_16x16x32_bf16(kf, qf[0][kk], sacc[0][g], 0, 0, 0);
        sacc[1][g] = __builtin_amdgcn_mfma_f32_16x16x32_bf16(kf, qf[1][kk], sacc[1][g], 0, 0, 0);
      }
    }
    __builtin_amdgcn_s_setprio(0);

    // in-register row softmax per rg (q = rg*16 + l15)
    float vmax[2];
#pragma unroll
    for (int rg = 0; rg < 2; ++rg) {
      float v = sacc[rg][0][0];
#pragma unroll
      for (int g = 0; g < 4; ++g)
#pragma unroll
        for (int j = 0; j < 4; ++j) v = fmaxf(v, sacc[rg][g][j]);
      v = fmaxf(v, __shfl_xor(v, 16));
      v = fmaxf(v, __shfl_xor(v, 32));
      vmax[rg] = v;
    }
    float grow = fmaxf(vmax[0] - mrow[0], vmax[1] - mrow[1]);
    if (__any(grow > 0.0f)) {
      float alpha[2];
#pragma unroll
      for (int rg = 0; rg < 2; ++rg) {
        float mnew = fmaxf(mrow[rg], vmax[rg]);
        alpha[rg] = __expf((mrow[rg] - mnew) * scale);
        mrow[rg] = mnew;
        lrow[rg] *= alpha[rg];
      }
      float ab[2][4];
#pragma unroll
      for (int rg = 0; rg < 2; ++rg)
#pragma unroll
        for (int j = 0; j < 4; ++j) ab[rg][j] = __shfl(alpha[rg], l4 * 4 + j);
#pragma unroll
      for (int nf = 0; nf < 16; ++nf)
#pragma unroll
        for (int rg = 0; rg < 2; ++rg) {
          oacc[rg][nf][0] *= ab[rg][0]; oacc[rg][nf][1] *= ab[rg][1];
          oacc[rg][nf][2] *= ab[rg][2]; oacc[rg][nf][3] *= ab[rg][3];
        }
    }
    float p[2][16];
#pragma unroll
    for (int rg = 0; rg < 2; ++rg) {
      const float msc = mrow[rg] * scale;
#pragma unroll
      for (int g = 0; g < 4; ++g)
#pragma unroll
        for (int j = 0; j < 4; ++j)
          p[rg][g * 4 + j] = __expf(fmaf(sacc[rg][g][j], scale, -msc));
      float r = ((p[rg][0] + p[rg][1]) + (p[rg][2] + p[rg][3]))
              + ((p[rg][4] + p[rg][5]) + (p[rg][6] + p[rg][7]))
              + ((p[rg][8] + p[rg][9]) + (p[rg][10] + p[rg][11]))
              + ((p[rg][12] + p[rg][13]) + (p[rg][14] + p[rg][15]));
      r += __shfl_xor(r, 16);
      r += __shfl_xor(r, 32);
      lrow[rg] += r;
    }

    // P pack (bf16 pairs) -> ds_write_b64 x 8, conflict-free swizzle
    u16* pl = &sP[wv][0];
#pragma unroll
    for (int rg = 0; rg < 2; ++rg)
#pragma unroll
      for (int g = 0; g < 4; ++g) {
        u32 lo = pk_bf16(p[rg][g * 4 + 0], p[rg][g * 4 + 1]);
        u32 hi = pk_bf16(p[rg][g * 4 + 2], p[rg][g * 4 + 3]);
        union { u32 w[2]; u16x4 v; } u;
        u.w[0] = lo; u.w[1] = hi;
        *reinterpret_cast<u16x4*>(
            pl + (rg * 16 + l15) * 64 + (((g * 4 + l4) ^ swp) << 2)) = u.v;
      }
    asm volatile("s_waitcnt lgkmcnt(0)" ::: "memory");
    __builtin_amdgcn_sched_barrier(0);

    // PV: O[q][d] += P[q][kv] @ V[kv][d]; vf shared across both rg
    __builtin_amdgcn_s_setprio(1);
#pragma unroll
    for (int c = 0; c < 2; ++c) {
      s16x8 paf[2];
#pragma unroll
      for (int rg = 0; rg < 2; ++rg)
        paf[rg] = *reinterpret_cast<const s16x8*>(
            pl + (rg * 16 + l15) * 64 + (((c * 8 + l4 * 2) ^ swp) << 2));
#pragma unroll
      for (int nf = 0; nf < 16; ++nf) {
        s16x8 vf = *reinterpret_cast<const s16x8*>(
            sVt + (nf * 16 + l15) * 64 + (((c * 4 + l4) ^ sw) << 3));
        oacc[0][nf] = __builtin_amdgcn_mfma_f32_16x16x32_bf16(paf[0], vf, oacc[0][nf], 0, 0, 0);
        oacc[1][nf] = __builtin_amdgcn_mfma_f32_16x16x32_bf16(paf[1], vf, oacc[1][nf], 0, 0, 0);
      }
    }
    __builtin_amdgcn_s_setprio(0);

    // all waves done reading this tile; restage (single buffer)
    __syncthreads();
    if (step + 1 < 32) {
      stageKV(step + 1);
      asm volatile("s_waitcnt vmcnt(0)" ::: "memory");
      __syncthreads();
    }
  }

  // epilogue: O/l, silu(gate), write activation for final GEMM
  float invl[2] = { 1.0f / lrow[0], 1.0f / lrow[1] };
  float ib[2][4];
#pragma unroll
  for (int rg = 0; rg < 2; ++rg)
#pragma unroll
    for (int j = 0; j < 4; ++j) ib[rg][j] = __shfl(invl[rg], l4 * 4 + j);
#pragma unroll
  for (int rg = 0; rg < 2; ++rg)
#pragma unroll
    for (int nf = 0; nf < 16; ++nf)
#pragma unroll
      for (int j = 0; j < 4; ++j) {
        const int srow = q0 + rg * 16 + l4 * 4 + j;
        const int d = nf * 16 + l15;
        float o = oacc[rg][nf][j] * ib[rg][j];
        float g = bf2f(qkv[(size_t)(b * S_N + srow) * QKVW + 2048 + h * 256 + d]);
        float sg = g / (1.0f + __expf(-g));
        act[(size_t)(b * S_N + srow) * 2048 + h * 256 + d] = f2bf(o * sg);
      }
}

extern "C" void kernel_launch(void* const* d_in, const int* in_sizes, int n_in,
                              void* d_out, int out_size, void* d_ws, size_t ws_size,
                              hipStream_t stream) {
  const float* hs  = (const float*)d_in[0];
  const int*   pos = (const int*)d_in[1];
  const float* Wq  = (const float*)d_in[2];
  const float* Wk  = (const float*)d_in[3];
  const float* Wv  = (const float*)d_in[4];
  const float* Wo  = (const float*)d_in[5];
  const float* qw  = (const float*)d_in[6];
  const float* kw  = (const float*)d_in[7];
  float* out = (float*)d_out;

  char* w8 = (char*)d_ws;
  u16* hs_bf   = (u16*)(w8);                    // 8,388,608 B
  u16* wqkv_bf = (u16*)(w8 + 8388608);          // 10,485,760
  u16* wo_bf   = (u16*)(w8 + 18874368);         // 4,194,304
  u16* qkv_raw = (u16*)(w8 + 23068672);         // 41,943,040
  u16* q_r     = (u16*)(w8 + 65011712);         // 16,777,216
  u16* k_r     = (u16*)(w8 + 81788928);         // 4,194,304
  u16* vt      = (u16*)(w8 + 85983232);         // 4,194,304
  u16* act     = (u16*)(w8 + 90177536);         // 16,777,216
  float* cost  = (float*)(w8 + 106954752);      // 262,144
  float* sint  = (float*)(w8 + 107216896);      // 262,144  -> total 107,479,040

  auto cast_launch = [&](const float* src, u16* dst, int n) {
    int n4 = n >> 2;
    int blocks = (n4 + 255) / 256;
    if (blocks > 2048) blocks = 2048;
    cast_bf16_kernel<<<blocks, 256, 0, stream>>>(src, dst, n4);
  };
  cast_launch(hs, hs_bf, B_N * S_N * HID_N);
  cast_launch(Wq, wqkv_bf, 4096 * 1024);
  cast_launch(Wk, wqkv_bf + 4194304, 512 * 1024);
  cast_launch(Wv, wqkv_bf + 4718592, 512 * 1024);
  cast_launch(Wo, wo_bf, 1024 * 2048);

  trig_kernel<<<(S_N * 32) / 256, 256, 0, stream>>>(pos, cost, sint);

  // QKV+gate projection: M=4096, N=5120, K=1024 -> qkv_raw bf16
  gemm_bt_kernel<1><<<32 * 40, 256, 0, stream>>>(hs_bf, wqkv_bf, (void*)qkv_raw, 4096, 5120, 1024);

  // RMSNorm + RoPE (q,k); V transpose
  normrope_kernel<<<(B_N * S_N * (H_N + HKV_N)) / 4, 256, 0, stream>>>(
      qkv_raw, qw, kw, cost, sint, q_r, k_r);
  vtrans_kernel<<<512, 256, 0, stream>>>(qkv_raw, vt);

  // attention + gating -> act bf16 (grid 256, 4 waves, 32 q-rows/wave, 2 blk/CU)
  attn_kernel<<<256, 256, 0, stream>>>(q_r, k_r, vt, qkv_raw, act);

  // output projection: M=4096, N=1024, K=2048 -> d_out fp32
  gemm_bt_kernel<0><<<32 * 8, 256, 0, stream>>>(act, wo_bf, (void*)out, 4096, 1024, 2048);
}

// Round 7
// 232.423 us; speedup vs baseline: 1.5683x; 1.5683x over previous
//
#include <hip/hip_runtime.h>
#include <math.h>

typedef unsigned short u16;
typedef unsigned int   u32;
typedef __attribute__((ext_vector_type(4))) float f32x4;
typedef __attribute__((ext_vector_type(8))) short s16x8;
typedef __attribute__((ext_vector_type(4))) unsigned short u16x4;

#define B_N   2
#define S_N   2048
#define HID_N 1024
#define H_N   8
#define HKV_N 2
#define D_N   256
#define QKVW  5120   // qkv_raw row width: 2048 q | 2048 gate | 512 k | 512 v

__device__ __forceinline__ u16 f2bf(float f) {
  union { float f; u32 u; } x; x.f = f;
  u32 r = x.u + 0x7FFFu + ((x.u >> 16) & 1u);
  return (u16)(r >> 16);
}
__device__ __forceinline__ float bf2f(u16 u) {
  union { u32 u; float f; } x; x.u = ((u32)u) << 16; return x.f;
}
__device__ __forceinline__ u32 pk_bf16(float lo, float hi) {
  u32 r;
  asm("v_cvt_pk_bf16_f32 %0, %1, %2" : "=v"(r) : "v"(lo), "v"(hi));
  return r;
}
__device__ __forceinline__ void gload_lds16(const u16* g, u16* l) {
  __builtin_amdgcn_global_load_lds((const __attribute__((address_space(1))) u32*)g,
                                   (__attribute__((address_space(3))) u32*)l, 16, 0, 0);
}

// ---------------- fp32 -> bf16 cast ----------------
__global__ __launch_bounds__(256)
void cast_bf16_kernel(const float* __restrict__ src, u16* __restrict__ dst, int n4) {
  int i = blockIdx.x * blockDim.x + threadIdx.x;
  int stride = gridDim.x * blockDim.x;
  for (; i < n4; i += stride) {
    float4 v = reinterpret_cast<const float4*>(src)[i];
    u16x4 o;
    o.x = f2bf(v.x); o.y = f2bf(v.y); o.z = f2bf(v.z); o.w = f2bf(v.w);
    reinterpret_cast<u16x4*>(dst)[i] = o;
  }
}

// ---------------- RoPE trig table ----------------
__global__ __launch_bounds__(256)
void trig_kernel(const int* __restrict__ pos, float* __restrict__ ct, float* __restrict__ st) {
  int i = blockIdx.x * blockDim.x + threadIdx.x;
  if (i >= S_N * 32) return;
  int s = i >> 5, j = i & 31;
  double inv = exp(-(double)j * (log(1.0e7) / 32.0));
  double ang = (double)pos[s] * inv;
  ct[i] = (float)cos(ang);
  st[i] = (float)sin(ang);
}

// ---------------- bf16 GEMM: C[M,N] = A[M,K] @ Bw[N,K]^T ----------------
// 128x128 tile, BK=32, 4 waves, counted-vmcnt double-buffer: next tile's
// global_load_lds stay in flight across the raw s_barrier (vmcnt(4) waits
// only for the current tile). __syncthreads is NOT used in the K-loop (it
// would emit vmcnt(0) and drain the prefetch queue).
template <int OUT_BF16>
__global__ __launch_bounds__(256, 2)
void gemm_bt_kernel(const u16* __restrict__ A, const u16* __restrict__ Bw,
                    void* __restrict__ Cout, int M, int N, int K) {
  const int nbn = N >> 7;
  const int bm = blockIdx.x / nbn;
  const int bn = blockIdx.x % nbn;
  const int tid = threadIdx.x;
  const int lane = tid & 63;
  const int wr = tid >> 7;
  const int wc = (tid >> 6) & 1;
  __shared__ u16 sA[2][128 * 32];
  __shared__ u16 sB[2][128 * 32];
  f32x4 acc[4][4] = {};
  const u16* Ab = A + (size_t)(bm << 7) * K;
  const u16* Bb = Bw + (size_t)(bn << 7) * K;
  const int r_st = tid >> 2;
  const int c_st = (tid & 3) * 8;
  const int nkt = K >> 5;

  auto stage = [&](int buf, int kt) {
    const int k0 = kt << 5;
    gload_lds16(Ab + (size_t)r_st * K + k0 + c_st,        &sA[buf][tid * 8]);
    gload_lds16(Ab + (size_t)(r_st + 64) * K + k0 + c_st, &sA[buf][2048 + tid * 8]);
    gload_lds16(Bb + (size_t)r_st * K + k0 + c_st,        &sB[buf][tid * 8]);
    gload_lds16(Bb + (size_t)(r_st + 64) * K + k0 + c_st, &sB[buf][2048 + tid * 8]);
  };

  stage(0, 0);
  int cur = 0;
  const int ra = (wr << 6) + (lane & 15);
  const int rb = (wc << 6) + (lane & 15);
  const int ks = (lane >> 4) << 3;
  for (int kt = 0; kt < nkt; ++kt) {
    if (kt + 1 < nkt) {
      stage(cur ^ 1, kt + 1);                       // issue next tile (4 loads)
      asm volatile("s_waitcnt vmcnt(4)" ::: "memory");  // wait current tile only
    } else {
      asm volatile("s_waitcnt vmcnt(0)" ::: "memory");
    }
    __builtin_amdgcn_s_barrier();
    const u16* sa = sA[cur];
    const u16* sb = sB[cur];
    s16x8 af[4], bfr[4];
#pragma unroll
    for (int m = 0; m < 4; ++m) af[m] = *reinterpret_cast<const s16x8*>(sa + (ra + m * 16) * 32 + ks);
#pragma unroll
    for (int n = 0; n < 4; ++n) bfr[n] = *reinterpret_cast<const s16x8*>(sb + (rb + n * 16) * 32 + ks);
#pragma unroll
    for (int m = 0; m < 4; ++m)
#pragma unroll
      for (int n = 0; n < 4; ++n)
        acc[m][n] = __builtin_amdgcn_mfma_f32_16x16x32_bf16(af[m], bfr[n], acc[m][n], 0, 0, 0);
    __builtin_amdgcn_s_barrier();                   // all reads of cur done
    cur ^= 1;
  }
  const int row0 = (bm << 7) + (wr << 6) + ((lane >> 4) << 2);
  const int col0 = (bn << 7) + (wc << 6) + (lane & 15);
#pragma unroll
  for (int m = 0; m < 4; ++m)
#pragma unroll
    for (int n = 0; n < 4; ++n)
#pragma unroll
      for (int j = 0; j < 4; ++j) {
        size_t idx = (size_t)(row0 + m * 16 + j) * N + col0 + n * 16;
        if (OUT_BF16) ((u16*)Cout)[idx] = f2bf(acc[m][n][j]);
        else          ((float*)Cout)[idx] = acc[m][n][j];
      }
}

// ---------------- RMSNorm + RoPE for q and k ----------------
__global__ __launch_bounds__(256)
void normrope_kernel(const u16* __restrict__ qkv, const float* __restrict__ qw,
                     const float* __restrict__ kw, const float* __restrict__ ct,
                     const float* __restrict__ st, u16* __restrict__ q_r,
                     u16* __restrict__ k_r) {
  const int lane = threadIdx.x & 63;
  const int row = blockIdx.x * 4 + (threadIdx.x >> 6);
  const int nq = B_N * S_N * H_N;
  const u16* src; u16* dst; const float* w;
  int s;
  if (row < nq) {
    int h = row & 7; int bs = row >> 3; s = bs & (S_N - 1); int b = bs >> 11;
    src = qkv + (size_t)(b * S_N + s) * QKVW + h * 256;
    dst = q_r + ((size_t)(b * H_N + h) * S_N + s) * 256;
    w = qw;
  } else {
    int r2 = row - nq;
    int h = r2 & 1; int bs = r2 >> 1; s = bs & (S_N - 1); int b = bs >> 11;
    src = qkv + (size_t)(b * S_N + s) * QKVW + 4096 + h * 256;
    dst = k_r + ((size_t)(b * HKV_N + h) * S_N + s) * 256;
    w = kw;
  }
  u16x4 xv = *reinterpret_cast<const u16x4*>(src + lane * 4);
  float x0 = bf2f(xv.x), x1 = bf2f(xv.y), x2 = bf2f(xv.z), x3 = bf2f(xv.w);
  float ss = x0 * x0 + x1 * x1 + x2 * x2 + x3 * x3;
#pragma unroll
  for (int off = 1; off < 64; off <<= 1) ss += __shfl_xor(ss, off);
  float rinv = rsqrtf(ss * (1.0f / 256.0f) + 1e-6f);
  float4 wv = *reinterpret_cast<const float4*>(w + lane * 4);
  float y[4] = { x0 * rinv * wv.x, x1 * rinv * wv.y, x2 * rinv * wv.z, x3 * rinv * wv.w };
  float p[4];
  p[0] = __shfl_xor(y[0], 8);
  p[1] = __shfl_xor(y[1], 8);
  p[2] = __shfl_xor(y[2], 8);
  p[3] = __shfl_xor(y[3], 8);
  if (lane < 16) {
    const float sgn = (lane < 8) ? -1.0f : 1.0f;
    const int jb = (lane * 4) & 31;
#pragma unroll
    for (int e = 0; e < 4; ++e) {
      float c = ct[(size_t)s * 32 + jb + e];
      float sn = st[(size_t)s * 32 + jb + e];
      y[e] = y[e] * c + sgn * p[e] * sn;
    }
  }
  u16x4 ov;
  ov.x = f2bf(y[0]); ov.y = f2bf(y[1]); ov.z = f2bf(y[2]); ov.w = f2bf(y[3]);
  *reinterpret_cast<u16x4*>(dst + lane * 4) = ov;
}

// ---------------- V transpose ----------------
__global__ __launch_bounds__(256)
void vtrans_kernel(const u16* __restrict__ qkv, u16* __restrict__ vt) {
  const int bid = blockIdx.x;            // 512
  const int dt = bid & 3;
  const int stile = (bid >> 2) & 31;
  const int bh = bid >> 7;
  const int b = bh >> 1, kvh = bh & 1;
  __shared__ u16 tile[64][68];
  const int t = threadIdx.x;
  const u16* src = qkv + (size_t)(b * S_N + stile * 64) * QKVW + 4608 + kvh * 256 + dt * 64;
#pragma unroll
  for (int i = 0; i < 2; ++i) {
    int sl = i * 32 + (t >> 3);
    int d8 = (t & 7) * 8;
    s16x8 v = *reinterpret_cast<const s16x8*>(src + (size_t)sl * QKVW + d8);
    u16x4 lo = { (u16)v[0], (u16)v[1], (u16)v[2], (u16)v[3] };
    u16x4 hi = { (u16)v[4], (u16)v[5], (u16)v[6], (u16)v[7] };
    *reinterpret_cast<u16x4*>(&tile[sl][d8]) = lo;
    *reinterpret_cast<u16x4*>(&tile[sl][d8 + 4]) = hi;
  }
  __syncthreads();
#pragma unroll
  for (int i = 0; i < 2; ++i) {
    int dl = i * 32 + (t >> 3);
    int s8 = (t & 7) * 8;
    u16 tmp[8];
#pragma unroll
    for (int e = 0; e < 8; ++e) tmp[e] = tile[s8 + e][dl];
    u16x4 lo = { tmp[0], tmp[1], tmp[2], tmp[3] };
    u16x4 hi = { tmp[4], tmp[5], tmp[6], tmp[7] };
    u16* dstp = vt + ((size_t)(bh * 256 + dt * 64 + dl)) * S_N + stile * 64 + s8;
    *reinterpret_cast<u16x4*>(dstp) = lo;
    *reinterpret_cast<u16x4*>(dstp + 4) = hi;
  }
}

// ---------------- flash attention + silu gating (r5 structure) ----------------
// 8 waves (512 thr); wave owns 16 q rows (q-tile 128); KVBLK=64; D=256.
// Swapped QK^T + in-register softmax + packed P (v_cvt_pk) -> ds_write_b64.
__global__ __launch_bounds__(512, 2)
void attn_kernel(const u16* __restrict__ q_r, const u16* __restrict__ k_r,
                 const u16* __restrict__ vt, const u16* __restrict__ qkv,
                 u16* __restrict__ act) {
  // XCD-aware remap: 2 XCDs per (b,kvh); K/V (2MB) fits per-XCD L2.
  const int dd = blockIdx.x;             // 0..255
  const int xcd = dd & 7;
  const int idx = dd >> 3;               // 0..31
  const int combo = xcd >> 1;            // b*2+kvh
  const int within = (xcd & 1) * 32 + idx;
  const int b = combo >> 1;
  const int kvh = combo & 1;
  const int h = kvh * 4 + (within >> 4);
  const int qt = within & 15;

  const int tid = threadIdx.x;
  const int lane = tid & 63;
  const int wv = tid >> 6;               // 0..7
  const int l15 = lane & 15;
  const int l4 = lane >> 4;

  __shared__ u16 sK[2][64 * 256];        // [kv][d], swizzled 16B slots
  __shared__ u16 sVt[2][256 * 64];       // [d][kv], swizzled
  __shared__ u16 sP[8][16 * 64];         // per-wave P tile, swizzled (8B slots)

  const int q0 = qt * 128 + wv * 16;
  const u16* qb = q_r + ((size_t)(b * H_N + h) * S_N + q0) * 256;
  s16x8 qf[8];
#pragma unroll
  for (int kk = 0; kk < 8; ++kk)
    qf[kk] = *reinterpret_cast<const s16x8*>(qb + (size_t)l15 * 256 + kk * 32 + l4 * 8);

  f32x4 oacc[16] = {};
  float mrow = -1e30f;
  float lrow = 0.f;

  const u16* kbase = k_r + ((size_t)(b * HKV_N + kvh) * S_N) * 256;
  const u16* vbase = vt + ((size_t)(b * HKV_N + kvh) * 256) * S_N;

  const int krow_b = tid >> 5;           // 0..15
  const int kp = tid & 31;
  const int vrow_b = tid >> 3;           // 0..63
  const int vp = tid & 7;

  auto stageKV = [&](int buf, int step) {
    const int kv0 = step << 6;
#pragma unroll
    for (int i = 0; i < 4; ++i) {
      const int krow = i * 16 + krow_b;
      gload_lds16(kbase + (size_t)(kv0 + krow) * 256 + ((kp ^ (krow_b & 7)) << 3),
                  &sK[buf][i * 4096 + tid * 8]);
    }
#pragma unroll
    for (int i = 0; i < 4; ++i) {
      const int vrow = i * 64 + vrow_b;
      gload_lds16(vbase + (size_t)vrow * S_N + kv0 + ((vp ^ (vrow_b & 7)) << 3),
                  &sVt[buf][i * 4096 + tid * 8]);
    }
  };

  stageKV(0, 0);
  int cur = 0;
  const float scale = 0.0625f;  // 1/sqrt(256)
  const int sw = l15 & 7;
  const int swp = l15 & 14;              // even XOR for 8B P slots
  for (int step = 0; step < 32; ++step) {
    asm volatile("s_waitcnt vmcnt(0)" ::: "memory");
    __builtin_amdgcn_s_barrier();
    if (step + 1 < 32) stageKV(cur ^ 1, step + 1);
    const u16* ktile = sK[cur];
    const u16* vtile = sVt[cur];

    // swapped QK^T: sacc[g] = S^T tile; lane holds q-col = l15,
    // kv-rows = g*16 + l4*4 + j
    f32x4 sacc[4] = {};
#pragma unroll
    for (int kk = 0; kk < 8; ++kk) {
      const int slot = kk * 4 + l4;
#pragma unroll
      for (int g = 0; g < 4; ++g) {
        s16x8 kf = *reinterpret_cast<const s16x8*>(
            ktile + (g * 16 + l15) * 256 + ((slot ^ sw) << 3));
        sacc[g] = __builtin_amdgcn_mfma_f32_16x16x32_bf16(kf, qf[kk], sacc[g], 0, 0, 0);
      }
    }

    // in-register row softmax (q = l15): per-lane reduce + 2 shuffles
    float vmax = sacc[0][0];
#pragma unroll
    for (int g = 0; g < 4; ++g)
#pragma unroll
      for (int j = 0; j < 4; ++j) vmax = fmaxf(vmax, sacc[g][j]);
    vmax = fmaxf(vmax, __shfl_xor(vmax, 16));
    vmax = fmaxf(vmax, __shfl_xor(vmax, 32));
    if (__any(vmax > mrow)) {
      float mnew = fmaxf(mrow, vmax);
      float alpha = __expf((mrow - mnew) * scale);
      mrow = mnew;
      lrow *= alpha;
      float ab[4];
#pragma unroll
      for (int j = 0; j < 4; ++j) ab[j] = __shfl(alpha, l4 * 4 + j);
#pragma unroll
      for (int nf = 0; nf < 16; ++nf) {
        oacc[nf][0] *= ab[0]; oacc[nf][1] *= ab[1];
        oacc[nf][2] *= ab[2]; oacc[nf][3] *= ab[3];
      }
    }
    const float msc = mrow * scale;
    float p[16];
#pragma unroll
    for (int g = 0; g < 4; ++g)
#pragma unroll
      for (int j = 0; j < 4; ++j)
        p[g * 4 + j] = __expf(fmaf(sacc[g][j], scale, -msc));
    float r = ((p[0] + p[1]) + (p[2] + p[3])) + ((p[4] + p[5]) + (p[6] + p[7]))
            + ((p[8] + p[9]) + (p[10] + p[11])) + ((p[12] + p[13]) + (p[14] + p[15]));
    r += __shfl_xor(r, 16);
    r += __shfl_xor(r, 32);
    lrow += r;

    // P pack (bf16 pairs) -> 4 x ds_write_b64, conflict-free swizzle
    u16* pl = &sP[wv][0];
#pragma unroll
    for (int g = 0; g < 4; ++g) {
      u32 lo = pk_bf16(p[g * 4 + 0], p[g * 4 + 1]);
      u32 hi = pk_bf16(p[g * 4 + 2], p[g * 4 + 3]);
      union { u32 w[2]; u16x4 v; } u;
      u.w[0] = lo; u.w[1] = hi;
      *reinterpret_cast<u16x4*>(pl + l15 * 64 + (((g * 4 + l4) ^ swp) << 2)) = u.v;
    }
    asm volatile("s_waitcnt lgkmcnt(0)" ::: "memory");
    __builtin_amdgcn_sched_barrier(0);

    // PV: O[q][d] += P[q][kv] @ V[kv][d]
#pragma unroll
    for (int c = 0; c < 2; ++c) {
      s16x8 paf = *reinterpret_cast<const s16x8*>(
          pl + l15 * 64 + (((c * 8 + l4 * 2) ^ swp) << 2));
#pragma unroll
      for (int nf = 0; nf < 16; ++nf) {
        s16x8 vf = *reinterpret_cast<const s16x8*>(
            vtile + (nf * 16 + l15) * 64 + (((c * 4 + l4) ^ sw) << 3));
        oacc[nf] = __builtin_amdgcn_mfma_f32_16x16x32_bf16(paf, vf, oacc[nf], 0, 0, 0);
      }
    }
    cur ^= 1;
  }

  // epilogue: O/l, silu(gate), write activation for final GEMM
  float invl = 1.0f / lrow;
  float ib[4];
#pragma unroll
  for (int j = 0; j < 4; ++j) ib[j] = __shfl(invl, l4 * 4 + j);
#pragma unroll
  for (int nf = 0; nf < 16; ++nf) {
#pragma unroll
    for (int j = 0; j < 4; ++j) {
      const int srow = q0 + l4 * 4 + j;
      const int d = nf * 16 + l15;
      float o = oacc[nf][j] * ib[j];
      float g = bf2f(qkv[(size_t)(b * S_N + srow) * QKVW + 2048 + h * 256 + d]);
      float sg = g / (1.0f + __expf(-g));
      act[(size_t)(b * S_N + srow) * 2048 + h * 256 + d] = f2bf(o * sg);
    }
  }
}

extern "C" void kernel_launch(void* const* d_in, const int* in_sizes, int n_in,
                              void* d_out, int out_size, void* d_ws, size_t ws_size,
                              hipStream_t stream) {
  const float* hs  = (const float*)d_in[0];
  const int*   pos = (const int*)d_in[1];
  const float* Wq  = (const float*)d_in[2];
  const float* Wk  = (const float*)d_in[3];
  const float* Wv  = (const float*)d_in[4];
  const float* Wo  = (const float*)d_in[5];
  const float* qw  = (const float*)d_in[6];
  const float* kw  = (const float*)d_in[7];
  float* out = (float*)d_out;

  char* w8 = (char*)d_ws;
  u16* hs_bf   = (u16*)(w8);                    // 8,388,608 B
  u16* wqkv_bf = (u16*)(w8 + 8388608);          // 10,485,760
  u16* wo_bf   = (u16*)(w8 + 18874368);         // 4,194,304
  u16* qkv_raw = (u16*)(w8 + 23068672);         // 41,943,040
  u16* q_r     = (u16*)(w8 + 65011712);         // 16,777,216
  u16* k_r     = (u16*)(w8 + 81788928);         // 4,194,304
  u16* vt      = (u16*)(w8 + 85983232);         // 4,194,304
  u16* act     = (u16*)(w8 + 90177536);         // 16,777,216
  float* cost  = (float*)(w8 + 106954752);      // 262,144
  float* sint  = (float*)(w8 + 107216896);      // 262,144  -> total 107,479,040

  auto cast_launch = [&](const float* src, u16* dst, int n) {
    int n4 = n >> 2;
    int blocks = (n4 + 255) / 256;
    if (blocks > 2048) blocks = 2048;
    cast_bf16_kernel<<<blocks, 256, 0, stream>>>(src, dst, n4);
  };
  cast_launch(hs, hs_bf, B_N * S_N * HID_N);
  cast_launch(Wq, wqkv_bf, 4096 * 1024);
  cast_launch(Wk, wqkv_bf + 4194304, 512 * 1024);
  cast_launch(Wv, wqkv_bf + 4718592, 512 * 1024);
  cast_launch(Wo, wo_bf, 1024 * 2048);

  trig_kernel<<<(S_N * 32) / 256, 256, 0, stream>>>(pos, cost, sint);

  // QKV+gate projection: M=4096, N=5120, K=1024 -> qkv_raw bf16
  gemm_bt_kernel<1><<<32 * 40, 256, 0, stream>>>(hs_bf, wqkv_bf, (void*)qkv_raw, 4096, 5120, 1024);

  // RMSNorm + RoPE (q,k); V transpose
  normrope_kernel<<<(B_N * S_N * (H_N + HKV_N)) / 4, 256, 0, stream>>>(
      qkv_raw, qw, kw, cost, sint, q_r, k_r);
  vtrans_kernel<<<512, 256, 0, stream>>>(qkv_raw, vt);

  // attention + gating -> act bf16 (grid 256 = 1 block/CU, 8 waves)
  attn_kernel<<<256, 512, 0, stream>>>(q_r, k_r, vt, qkv_raw, act);

  // output projection: M=4096, N=1024, K=2048 -> d_out fp32
  gemm_bt_kernel<0><<<32 * 8, 256, 0, stream>>>(act, wo_bf, (void*)out, 4096, 1024, 2048);
}

// Round 8
// 228.201 us; speedup vs baseline: 1.5973x; 1.0185x over previous
//
#include <hip/hip_runtime.h>
#include <math.h>

typedef unsigned short u16;
typedef unsigned int   u32;
typedef __attribute__((ext_vector_type(4))) float f32x4;
typedef __attribute__((ext_vector_type(8))) short s16x8;
typedef __attribute__((ext_vector_type(4))) unsigned short u16x4;

#define B_N   2
#define S_N   2048
#define HID_N 1024
#define H_N   8
#define HKV_N 2
#define D_N   256
#define QKVW  5120   // qkv_raw row width: 2048 q | 2048 gate | 512 k | 512 v

__device__ __forceinline__ u16 f2bf(float f) {
  union { float f; u32 u; } x; x.f = f;
  u32 r = x.u + 0x7FFFu + ((x.u >> 16) & 1u);
  return (u16)(r >> 16);
}
__device__ __forceinline__ float bf2f(u16 u) {
  union { u32 u; float f; } x; x.u = ((u32)u) << 16; return x.f;
}
__device__ __forceinline__ u32 pk_bf16(float lo, float hi) {
  u32 r;
  asm("v_cvt_pk_bf16_f32 %0, %1, %2" : "=v"(r) : "v"(lo), "v"(hi));
  return r;
}
__device__ __forceinline__ void gload_lds16(const u16* g, u16* l) {
  __builtin_amdgcn_global_load_lds((const __attribute__((address_space(1))) u32*)g,
                                   (__attribute__((address_space(3))) u32*)l, 16, 0, 0);
}

// ---------------- fp32 -> bf16 cast ----------------
__global__ __launch_bounds__(256)
void cast_bf16_kernel(const float* __restrict__ src, u16* __restrict__ dst, int n4) {
  int i = blockIdx.x * blockDim.x + threadIdx.x;
  int stride = gridDim.x * blockDim.x;
  for (; i < n4; i += stride) {
    float4 v = reinterpret_cast<const float4*>(src)[i];
    u16x4 o;
    o.x = f2bf(v.x); o.y = f2bf(v.y); o.z = f2bf(v.z); o.w = f2bf(v.w);
    reinterpret_cast<u16x4*>(dst)[i] = o;
  }
}

// ---------------- RoPE trig table ----------------
__global__ __launch_bounds__(256)
void trig_kernel(const int* __restrict__ pos, float* __restrict__ ct, float* __restrict__ st) {
  int i = blockIdx.x * blockDim.x + threadIdx.x;
  if (i >= S_N * 32) return;
  int s = i >> 5, j = i & 31;
  double inv = exp(-(double)j * (log(1.0e7) / 32.0));
  double ang = (double)pos[s] * inv;
  ct[i] = (float)cos(ang);
  st[i] = (float)sin(ang);
}

// ---------------- bf16 GEMM: C[M,N] = A[M,K] @ Bw[N,K]^T ----------------
// 128x128 tile, BK=32, 4 waves. 3-deep staging pipeline: tile kt+2 issued at
// iteration kt top; s_waitcnt vmcnt(8) leaves 8 loads in flight across the
// barrier (~2 iterations of latency cover). XCD super-tile remap: block g runs
// on XCD g%8; each XCD owns a 32bm x bn_per_x super-tile so its B panels stay
// resident in its private 4MB L2.
template <int OUT_BF16>
__global__ __launch_bounds__(256, 3)
void gemm_bt_kernel(const u16* __restrict__ A, const u16* __restrict__ Bw,
                    void* __restrict__ Cout, int M, int N, int K, int bn_per_x) {
  const int x = blockIdx.x & 7;
  const int i = blockIdx.x >> 3;
  const int bm = i / bn_per_x;
  const int bn = x * bn_per_x + (i - bm * bn_per_x);
  const int tid = threadIdx.x;
  const int lane = tid & 63;
  const int wr = tid >> 7;
  const int wc = (tid >> 6) & 1;
  __shared__ u16 sA[3][128 * 32];
  __shared__ u16 sB[3][128 * 32];
  f32x4 acc[4][4] = {};
  const u16* Ab = A + (size_t)(bm << 7) * K;
  const u16* Bb = Bw + (size_t)(bn << 7) * K;
  const int r_st = tid >> 2;
  const int c_st = (tid & 3) * 8;
  const int nkt = K >> 5;

  auto stage = [&](int buf, int kt) {
    const int k0 = kt << 5;
    gload_lds16(Ab + (size_t)r_st * K + k0 + c_st,        &sA[buf][tid * 8]);
    gload_lds16(Ab + (size_t)(r_st + 64) * K + k0 + c_st, &sA[buf][2048 + tid * 8]);
    gload_lds16(Bb + (size_t)r_st * K + k0 + c_st,        &sB[buf][tid * 8]);
    gload_lds16(Bb + (size_t)(r_st + 64) * K + k0 + c_st, &sB[buf][2048 + tid * 8]);
  };

  stage(0, 0);
  stage(1, 1);
  const int ra = (wr << 6) + (lane & 15);
  const int rb = (wc << 6) + (lane & 15);
  const int ks = (lane >> 4) << 3;
  int cb = 0;                             // kt % 3
  for (int kt = 0; kt < nkt; ++kt) {
    if (kt + 2 < nkt) {
      int nb = cb + 2; if (nb >= 3) nb -= 3;
      stage(nb, kt + 2);                  // issue tile kt+2 (4 loads)
      asm volatile("s_waitcnt vmcnt(8)" ::: "memory");  // tile kt complete
    } else if (kt + 1 < nkt) {
      asm volatile("s_waitcnt vmcnt(4)" ::: "memory");
    } else {
      asm volatile("s_waitcnt vmcnt(0)" ::: "memory");
    }
    __builtin_amdgcn_s_barrier();
    const u16* sa = sA[cb];
    const u16* sb = sB[cb];
    s16x8 af[4], bfr[4];
#pragma unroll
    for (int m = 0; m < 4; ++m) af[m] = *reinterpret_cast<const s16x8*>(sa + (ra + m * 16) * 32 + ks);
#pragma unroll
    for (int n = 0; n < 4; ++n) bfr[n] = *reinterpret_cast<const s16x8*>(sb + (rb + n * 16) * 32 + ks);
#pragma unroll
    for (int m = 0; m < 4; ++m)
#pragma unroll
      for (int n = 0; n < 4; ++n)
        acc[m][n] = __builtin_amdgcn_mfma_f32_16x16x32_bf16(af[m], bfr[n], acc[m][n], 0, 0, 0);
    __builtin_amdgcn_s_barrier();         // all reads of cb done
    ++cb; if (cb >= 3) cb -= 3;
  }
  const int row0 = (bm << 7) + (wr << 6) + ((lane >> 4) << 2);
  const int col0 = (bn << 7) + (wc << 6) + (lane & 15);
#pragma unroll
  for (int m = 0; m < 4; ++m)
#pragma unroll
    for (int n = 0; n < 4; ++n)
#pragma unroll
      for (int j = 0; j < 4; ++j) {
        size_t idx = (size_t)(row0 + m * 16 + j) * N + col0 + n * 16;
        if (OUT_BF16) ((u16*)Cout)[idx] = f2bf(acc[m][n][j]);
        else          ((float*)Cout)[idx] = acc[m][n][j];
      }
}

// ---------------- RMSNorm + RoPE for q and k ----------------
__global__ __launch_bounds__(256)
void normrope_kernel(const u16* __restrict__ qkv, const float* __restrict__ qw,
                     const float* __restrict__ kw, const float* __restrict__ ct,
                     const float* __restrict__ st, u16* __restrict__ q_r,
                     u16* __restrict__ k_r) {
  const int lane = threadIdx.x & 63;
  const int row = blockIdx.x * 4 + (threadIdx.x >> 6);
  const int nq = B_N * S_N * H_N;
  const u16* src; u16* dst; const float* w;
  int s;
  if (row < nq) {
    int h = row & 7; int bs = row >> 3; s = bs & (S_N - 1); int b = bs >> 11;
    src = qkv + (size_t)(b * S_N + s) * QKVW + h * 256;
    dst = q_r + ((size_t)(b * H_N + h) * S_N + s) * 256;
    w = qw;
  } else {
    int r2 = row - nq;
    int h = r2 & 1; int bs = r2 >> 1; s = bs & (S_N - 1); int b = bs >> 11;
    src = qkv + (size_t)(b * S_N + s) * QKVW + 4096 + h * 256;
    dst = k_r + ((size_t)(b * HKV_N + h) * S_N + s) * 256;
    w = kw;
  }
  u16x4 xv = *reinterpret_cast<const u16x4*>(src + lane * 4);
  float x0 = bf2f(xv.x), x1 = bf2f(xv.y), x2 = bf2f(xv.z), x3 = bf2f(xv.w);
  float ss = x0 * x0 + x1 * x1 + x2 * x2 + x3 * x3;
#pragma unroll
  for (int off = 1; off < 64; off <<= 1) ss += __shfl_xor(ss, off);
  float rinv = rsqrtf(ss * (1.0f / 256.0f) + 1e-6f);
  float4 wv = *reinterpret_cast<const float4*>(w + lane * 4);
  float y[4] = { x0 * rinv * wv.x, x1 * rinv * wv.y, x2 * rinv * wv.z, x3 * rinv * wv.w };
  float p[4];
  p[0] = __shfl_xor(y[0], 8);
  p[1] = __shfl_xor(y[1], 8);
  p[2] = __shfl_xor(y[2], 8);
  p[3] = __shfl_xor(y[3], 8);
  if (lane < 16) {
    const float sgn = (lane < 8) ? -1.0f : 1.0f;
    const int jb = (lane * 4) & 31;
#pragma unroll
    for (int e = 0; e < 4; ++e) {
      float c = ct[(size_t)s * 32 + jb + e];
      float sn = st[(size_t)s * 32 + jb + e];
      y[e] = y[e] * c + sgn * p[e] * sn;
    }
  }
  u16x4 ov;
  ov.x = f2bf(y[0]); ov.y = f2bf(y[1]); ov.z = f2bf(y[2]); ov.w = f2bf(y[3]);
  *reinterpret_cast<u16x4*>(dst + lane * 4) = ov;
}

// ---------------- V transpose ----------------
__global__ __launch_bounds__(256)
void vtrans_kernel(const u16* __restrict__ qkv, u16* __restrict__ vt) {
  const int bid = blockIdx.x;            // 512
  const int dt = bid & 3;
  const int stile = (bid >> 2) & 31;
  const int bh = bid >> 7;
  const int b = bh >> 1, kvh = bh & 1;
  __shared__ u16 tile[64][68];
  const int t = threadIdx.x;
  const u16* src = qkv + (size_t)(b * S_N + stile * 64) * QKVW + 4608 + kvh * 256 + dt * 64;
#pragma unroll
  for (int i = 0; i < 2; ++i) {
    int sl = i * 32 + (t >> 3);
    int d8 = (t & 7) * 8;
    s16x8 v = *reinterpret_cast<const s16x8*>(src + (size_t)sl * QKVW + d8);
    u16x4 lo = { (u16)v[0], (u16)v[1], (u16)v[2], (u16)v[3] };
    u16x4 hi = { (u16)v[4], (u16)v[5], (u16)v[6], (u16)v[7] };
    *reinterpret_cast<u16x4*>(&tile[sl][d8]) = lo;
    *reinterpret_cast<u16x4*>(&tile[sl][d8 + 4]) = hi;
  }
  __syncthreads();
#pragma unroll
  for (int i = 0; i < 2; ++i) {
    int dl = i * 32 + (t >> 3);
    int s8 = (t & 7) * 8;
    u16 tmp[8];
#pragma unroll
    for (int e = 0; e < 8; ++e) tmp[e] = tile[s8 + e][dl];
    u16x4 lo = { tmp[0], tmp[1], tmp[2], tmp[3] };
    u16x4 hi = { tmp[4], tmp[5], tmp[6], tmp[7] };
    u16* dstp = vt + ((size_t)(bh * 256 + dt * 64 + dl)) * S_N + stile * 64 + s8;
    *reinterpret_cast<u16x4*>(dstp) = lo;
    *reinterpret_cast<u16x4*>(dstp + 4) = hi;
  }
}

// ---------------- flash attention + silu gating (r5 structure) ----------------
// 8 waves (512 thr); wave owns 16 q rows (q-tile 128); KVBLK=64; D=256.
// Swapped QK^T + in-register softmax + packed P (v_cvt_pk) -> ds_write_b64.
__global__ __launch_bounds__(512, 2)
void attn_kernel(const u16* __restrict__ q_r, const u16* __restrict__ k_r,
                 const u16* __restrict__ vt, const u16* __restrict__ qkv,
                 u16* __restrict__ act) {
  // XCD-aware remap: 2 XCDs per (b,kvh); K/V (2MB) fits per-XCD L2.
  const int dd = blockIdx.x;             // 0..255
  const int xcd = dd & 7;
  const int idx = dd >> 3;               // 0..31
  const int combo = xcd >> 1;            // b*2+kvh
  const int within = (xcd & 1) * 32 + idx;
  const int b = combo >> 1;
  const int kvh = combo & 1;
  const int h = kvh * 4 + (within >> 4);
  const int qt = within & 15;

  const int tid = threadIdx.x;
  const int lane = tid & 63;
  const int wv = tid >> 6;               // 0..7
  const int l15 = lane & 15;
  const int l4 = lane >> 4;

  __shared__ u16 sK[2][64 * 256];        // [kv][d], swizzled 16B slots
  __shared__ u16 sVt[2][256 * 64];       // [d][kv], swizzled
  __shared__ u16 sP[8][16 * 64];         // per-wave P tile, swizzled (8B slots)

  const int q0 = qt * 128 + wv * 16;
  const u16* qb = q_r + ((size_t)(b * H_N + h) * S_N + q0) * 256;
  s16x8 qf[8];
#pragma unroll
  for (int kk = 0; kk < 8; ++kk)
    qf[kk] = *reinterpret_cast<const s16x8*>(qb + (size_t)l15 * 256 + kk * 32 + l4 * 8);

  f32x4 oacc[16] = {};
  float mrow = -1e30f;
  float lrow = 0.f;

  const u16* kbase = k_r + ((size_t)(b * HKV_N + kvh) * S_N) * 256;
  const u16* vbase = vt + ((size_t)(b * HKV_N + kvh) * 256) * S_N;

  const int krow_b = tid >> 5;           // 0..15
  const int kp = tid & 31;
  const int vrow_b = tid >> 3;           // 0..63
  const int vp = tid & 7;

  auto stageKV = [&](int buf, int step) {
    const int kv0 = step << 6;
#pragma unroll
    for (int i = 0; i < 4; ++i) {
      const int krow = i * 16 + krow_b;
      gload_lds16(kbase + (size_t)(kv0 + krow) * 256 + ((kp ^ (krow_b & 7)) << 3),
                  &sK[buf][i * 4096 + tid * 8]);
    }
#pragma unroll
    for (int i = 0; i < 4; ++i) {
      const int vrow = i * 64 + vrow_b;
      gload_lds16(vbase + (size_t)vrow * S_N + kv0 + ((vp ^ (vrow_b & 7)) << 3),
                  &sVt[buf][i * 4096 + tid * 8]);
    }
  };

  stageKV(0, 0);
  int cur = 0;
  const float scale = 0.0625f;  // 1/sqrt(256)
  const int sw = l15 & 7;
  const int swp = l15 & 14;              // even XOR for 8B P slots
  for (int step = 0; step < 32; ++step) {
    asm volatile("s_waitcnt vmcnt(0)" ::: "memory");
    __builtin_amdgcn_s_barrier();
    if (step + 1 < 32) stageKV(cur ^ 1, step + 1);
    const u16* ktile = sK[cur];
    const u16* vtile = sVt[cur];

    // swapped QK^T: sacc[g] = S^T tile; lane holds q-col = l15,
    // kv-rows = g*16 + l4*4 + j
    f32x4 sacc[4] = {};
#pragma unroll
    for (int kk = 0; kk < 8; ++kk) {
      const int slot = kk * 4 + l4;
#pragma unroll
      for (int g = 0; g < 4; ++g) {
        s16x8 kf = *reinterpret_cast<const s16x8*>(
            ktile + (g * 16 + l15) * 256 + ((slot ^ sw) << 3));
        sacc[g] = __builtin_amdgcn_mfma_f32_16x16x32_bf16(kf, qf[kk], sacc[g], 0, 0, 0);
      }
    }

    // in-register row softmax (q = l15): per-lane reduce + 2 shuffles
    float vmax = sacc[0][0];
#pragma unroll
    for (int g = 0; g < 4; ++g)
#pragma unroll
      for (int j = 0; j < 4; ++j) vmax = fmaxf(vmax, sacc[g][j]);
    vmax = fmaxf(vmax, __shfl_xor(vmax, 16));
    vmax = fmaxf(vmax, __shfl_xor(vmax, 32));
    if (__any(vmax > mrow)) {
      float mnew = fmaxf(mrow, vmax);
      float alpha = __expf((mrow - mnew) * scale);
      mrow = mnew;
      lrow *= alpha;
      float ab[4];
#pragma unroll
      for (int j = 0; j < 4; ++j) ab[j] = __shfl(alpha, l4 * 4 + j);
#pragma unroll
      for (int nf = 0; nf < 16; ++nf) {
        oacc[nf][0] *= ab[0]; oacc[nf][1] *= ab[1];
        oacc[nf][2] *= ab[2]; oacc[nf][3] *= ab[3];
      }
    }
    const float msc = mrow * scale;
    float p[16];
#pragma unroll
    for (int g = 0; g < 4; ++g)
#pragma unroll
      for (int j = 0; j < 4; ++j)
        p[g * 4 + j] = __expf(fmaf(sacc[g][j], scale, -msc));
    float r = ((p[0] + p[1]) + (p[2] + p[3])) + ((p[4] + p[5]) + (p[6] + p[7]))
            + ((p[8] + p[9]) + (p[10] + p[11])) + ((p[12] + p[13]) + (p[14] + p[15]));
    r += __shfl_xor(r, 16);
    r += __shfl_xor(r, 32);
    lrow += r;

    // P pack (bf16 pairs) -> 4 x ds_write_b64, conflict-free swizzle
    u16* pl = &sP[wv][0];
#pragma unroll
    for (int g = 0; g < 4; ++g) {
      u32 lo = pk_bf16(p[g * 4 + 0], p[g * 4 + 1]);
      u32 hi = pk_bf16(p[g * 4 + 2], p[g * 4 + 3]);
      union { u32 w[2]; u16x4 v; } u;
      u.w[0] = lo; u.w[1] = hi;
      *reinterpret_cast<u16x4*>(pl + l15 * 64 + (((g * 4 + l4) ^ swp) << 2)) = u.v;
    }
    asm volatile("s_waitcnt lgkmcnt(0)" ::: "memory");
    __builtin_amdgcn_sched_barrier(0);

    // PV: O[q][d] += P[q][kv] @ V[kv][d]
#pragma unroll
    for (int c = 0; c < 2; ++c) {
      s16x8 paf = *reinterpret_cast<const s16x8*>(
          pl + l15 * 64 + (((c * 8 + l4 * 2) ^ swp) << 2));
#pragma unroll
      for (int nf = 0; nf < 16; ++nf) {
        s16x8 vf = *reinterpret_cast<const s16x8*>(
            vtile + (nf * 16 + l15) * 64 + (((c * 4 + l4) ^ sw) << 3));
        oacc[nf] = __builtin_amdgcn_mfma_f32_16x16x32_bf16(paf, vf, oacc[nf], 0, 0, 0);
      }
    }
    cur ^= 1;
  }

  // epilogue: O/l, silu(gate), write activation for final GEMM
  float invl = 1.0f / lrow;
  float ib[4];
#pragma unroll
  for (int j = 0; j < 4; ++j) ib[j] = __shfl(invl, l4 * 4 + j);
#pragma unroll
  for (int nf = 0; nf < 16; ++nf) {
#pragma unroll
    for (int j = 0; j < 4; ++j) {
      const int srow = q0 + l4 * 4 + j;
      const int d = nf * 16 + l15;
      float o = oacc[nf][j] * ib[j];
      float g = bf2f(qkv[(size_t)(b * S_N + srow) * QKVW + 2048 + h * 256 + d]);
      float sg = g / (1.0f + __expf(-g));
      act[(size_t)(b * S_N + srow) * 2048 + h * 256 + d] = f2bf(o * sg);
    }
  }
}

extern "C" void kernel_launch(void* const* d_in, const int* in_sizes, int n_in,
                              void* d_out, int out_size, void* d_ws, size_t ws_size,
                              hipStream_t stream) {
  const float* hs  = (const float*)d_in[0];
  const int*   pos = (const int*)d_in[1];
  const float* Wq  = (const float*)d_in[2];
  const float* Wk  = (const float*)d_in[3];
  const float* Wv  = (const float*)d_in[4];
  const float* Wo  = (const float*)d_in[5];
  const float* qw  = (const float*)d_in[6];
  const float* kw  = (const float*)d_in[7];
  float* out = (float*)d_out;

  char* w8 = (char*)d_ws;
  u16* hs_bf   = (u16*)(w8);                    // 8,388,608 B
  u16* wqkv_bf = (u16*)(w8 + 8388608);          // 10,485,760
  u16* wo_bf   = (u16*)(w8 + 18874368);         // 4,194,304
  u16* qkv_raw = (u16*)(w8 + 23068672);         // 41,943,040
  u16* q_r     = (u16*)(w8 + 65011712);         // 16,777,216
  u16* k_r     = (u16*)(w8 + 81788928);         // 4,194,304
  u16* vt      = (u16*)(w8 + 85983232);         // 4,194,304
  u16* act     = (u16*)(w8 + 90177536);         // 16,777,216
  float* cost  = (float*)(w8 + 106954752);      // 262,144
  float* sint  = (float*)(w8 + 107216896);      // 262,144  -> total 107,479,040

  auto cast_launch = [&](const float* src, u16* dst, int n) {
    int n4 = n >> 2;
    int blocks = (n4 + 255) / 256;
    if (blocks > 2048) blocks = 2048;
    cast_bf16_kernel<<<blocks, 256, 0, stream>>>(src, dst, n4);
  };
  cast_launch(hs, hs_bf, B_N * S_N * HID_N);
  cast_launch(Wq, wqkv_bf, 4096 * 1024);
  cast_launch(Wk, wqkv_bf + 4194304, 512 * 1024);
  cast_launch(Wv, wqkv_bf + 4718592, 512 * 1024);
  cast_launch(Wo, wo_bf, 1024 * 2048);

  trig_kernel<<<(S_N * 32) / 256, 256, 0, stream>>>(pos, cost, sint);

  // QKV+gate projection: M=4096, N=5120, K=1024 -> qkv_raw bf16
  // grid 1280 = 8 XCDs x (32 bm x 5 bn)
  gemm_bt_kernel<1><<<1280, 256, 0, stream>>>(hs_bf, wqkv_bf, (void*)qkv_raw,
                                              4096, 5120, 1024, 5);

  // RMSNorm + RoPE (q,k); V transpose
  normrope_kernel<<<(B_N * S_N * (H_N + HKV_N)) / 4, 256, 0, stream>>>(
      qkv_raw, qw, kw, cost, sint, q_r, k_r);
  vtrans_kernel<<<512, 256, 0, stream>>>(qkv_raw, vt);

  // attention + gating -> act bf16 (grid 256 = 1 block/CU, 8 waves)
  attn_kernel<<<256, 512, 0, stream>>>(q_r, k_r, vt, qkv_raw, act);

  // output projection: M=4096, N=1024, K=2048 -> d_out fp32
  // grid 256 = 8 XCDs x (32 bm x 1 bn)
  gemm_bt_kernel<0><<<256, 256, 0, stream>>>(act, wo_bf, (void*)out,
                                             4096, 1024, 2048, 1);
}

// Round 9
// 220.752 us; speedup vs baseline: 1.6512x; 1.0337x over previous
//
#include <hip/hip_runtime.h>
#include <math.h>

typedef unsigned short u16;
typedef unsigned int   u32;
typedef __attribute__((ext_vector_type(4))) float f32x4;
typedef __attribute__((ext_vector_type(8))) short s16x8;
typedef __attribute__((ext_vector_type(4))) unsigned short u16x4;

#define B_N   2
#define S_N   2048
#define HID_N 1024
#define H_N   8
#define HKV_N 2
#define D_N   256
#define QKVW  5120   // qkv_raw row width: 2048 q | 2048 gate | 512 k | 512 v

__device__ __forceinline__ u16 f2bf(float f) {
  union { float f; u32 u; } x; x.f = f;
  u32 r = x.u + 0x7FFFu + ((x.u >> 16) & 1u);
  return (u16)(r >> 16);
}
__device__ __forceinline__ float bf2f(u16 u) {
  union { u32 u; float f; } x; x.u = ((u32)u) << 16; return x.f;
}
__device__ __forceinline__ u32 pk_bf16(float lo, float hi) {
  u32 r;
  asm("v_cvt_pk_bf16_f32 %0, %1, %2" : "=v"(r) : "v"(lo), "v"(hi));
  return r;
}
__device__ __forceinline__ void gload_lds16(const u16* g, u16* l) {
  __builtin_amdgcn_global_load_lds((const __attribute__((address_space(1))) u32*)g,
                                   (__attribute__((address_space(3))) u32*)l, 16, 0, 0);
}

// ---------------- fused fp32 -> bf16 casts (5 segments) ----------------
#define N4_HS 1048576
#define N4_WQ 1048576
#define N4_WK 131072
#define N4_WV 131072
#define N4_WO 524288
#define N4_TOT (N4_HS + N4_WQ + N4_WK + N4_WV + N4_WO)

__global__ __launch_bounds__(256)
void cast5_kernel(const float* __restrict__ hs, const float* __restrict__ wq,
                  const float* __restrict__ wk, const float* __restrict__ wv,
                  const float* __restrict__ wo, u16* __restrict__ hs_bf,
                  u16* __restrict__ wqkv_bf, u16* __restrict__ wo_bf) {
  int i = blockIdx.x * blockDim.x + threadIdx.x;
  const int stride = gridDim.x * blockDim.x;
  for (; i < N4_TOT; i += stride) {
    const float* src; u16* dst; int k;
    if (i < N4_HS)                         { src = hs; dst = hs_bf; k = i; }
    else if (i < N4_HS + N4_WQ)            { src = wq; dst = wqkv_bf; k = i - N4_HS; }
    else if (i < N4_HS + N4_WQ + N4_WK)    { src = wk; dst = wqkv_bf + 4194304; k = i - (N4_HS + N4_WQ); }
    else if (i < N4_TOT - N4_WO)           { src = wv; dst = wqkv_bf + 4718592; k = i - (N4_HS + N4_WQ + N4_WK); }
    else                                   { src = wo; dst = wo_bf; k = i - (N4_TOT - N4_WO); }
    float4 v = reinterpret_cast<const float4*>(src)[k];
    u16x4 o;
    o.x = f2bf(v.x); o.y = f2bf(v.y); o.z = f2bf(v.z); o.w = f2bf(v.w);
    reinterpret_cast<u16x4*>(dst)[k] = o;
  }
}

// ---------------- RoPE trig table ----------------
__global__ __launch_bounds__(256)
void trig_kernel(const int* __restrict__ pos, float* __restrict__ ct, float* __restrict__ st) {
  int i = blockIdx.x * blockDim.x + threadIdx.x;
  if (i >= S_N * 32) return;
  int s = i >> 5, j = i & 31;
  double inv = exp(-(double)j * (log(1.0e7) / 32.0));
  double ang = (double)pos[s] * inv;
  ct[i] = (float)cos(ang);
  st[i] = (float)sin(ang);
}

// ---------------- bf16 GEMM: C[M,N] = A[M,K] @ Bw[N,K]^T ----------------
// 128x128 tile, BK=64, 4 waves, XOR-swizzled LDS (T2): slot s of row r holds
// global col-slot s^(r&7); fragment reads then hit all 32 banks (2-way = free)
// instead of the 8-way conflict of the BK=32 layout. Double-buffered with
// counted vmcnt(8) across raw barriers; XCD super-tile remap for L2 residency.
template <int OUT_BF16>
__global__ __launch_bounds__(256, 2)
void gemm_bt_kernel(const u16* __restrict__ A, const u16* __restrict__ Bw,
                    void* __restrict__ Cout, int M, int N, int K, int bn_per_x) {
  const int x = blockIdx.x & 7;
  const int i0 = blockIdx.x >> 3;
  const int bm = i0 / bn_per_x;
  const int bn = x * bn_per_x + (i0 - bm * bn_per_x);
  const int tid = threadIdx.x;
  const int lane = tid & 63;
  const int wr = tid >> 7;
  const int wc = (tid >> 6) & 1;
  __shared__ u16 sA[2][128 * 64];
  __shared__ u16 sB[2][128 * 64];
  f32x4 acc[4][4] = {};
  const u16* Ab = A + (size_t)(bm << 7) * K;
  const u16* Bb = Bw + (size_t)(bn << 7) * K;
  const int nkt = K >> 6;

  auto stage = [&](int buf, int kt) {
    const int k0 = kt << 6;
#pragma unroll
    for (int i = 0; i < 4; ++i) {
      const int L = i * 256 + tid;
      const int r = L >> 3, s = L & 7;
      gload_lds16(Ab + (size_t)r * K + k0 + ((s ^ (r & 7)) << 3), &sA[buf][L * 8]);
    }
#pragma unroll
    for (int i = 0; i < 4; ++i) {
      const int L = i * 256 + tid;
      const int r = L >> 3, s = L & 7;
      gload_lds16(Bb + (size_t)r * K + k0 + ((s ^ (r & 7)) << 3), &sB[buf][L * 8]);
    }
  };

  stage(0, 0);
  int cur = 0;
  const int ra = (wr << 6) + (lane & 15);
  const int rb = (wc << 6) + (lane & 15);
  const int l4 = (lane >> 4);
  const int sw = lane & 7;               // (row&7) is uniform = l15&7 = lane&7
  for (int kt = 0; kt < nkt; ++kt) {
    if (kt + 1 < nkt) {
      stage(cur ^ 1, kt + 1);                           // 8 loads in flight
      asm volatile("s_waitcnt vmcnt(8)" ::: "memory");  // current tile done
    } else {
      asm volatile("s_waitcnt vmcnt(0)" ::: "memory");
    }
    __builtin_amdgcn_s_barrier();
    const u16* sa = sA[cur];
    const u16* sb = sB[cur];
#pragma unroll
    for (int kk = 0; kk < 2; ++kk) {
      const int sl = ((kk * 4 + l4) ^ sw) << 3;
      s16x8 af[4], bfr[4];
#pragma unroll
      for (int m = 0; m < 4; ++m)
        af[m] = *reinterpret_cast<const s16x8*>(sa + (ra + m * 16) * 64 + sl);
#pragma unroll
      for (int n = 0; n < 4; ++n)
        bfr[n] = *reinterpret_cast<const s16x8*>(sb + (rb + n * 16) * 64 + sl);
#pragma unroll
      for (int m = 0; m < 4; ++m)
#pragma unroll
        for (int n = 0; n < 4; ++n)
          acc[m][n] = __builtin_amdgcn_mfma_f32_16x16x32_bf16(af[m], bfr[n], acc[m][n], 0, 0, 0);
    }
    __builtin_amdgcn_s_barrier();
    cur ^= 1;
  }
  const int row0 = (bm << 7) + (wr << 6) + ((lane >> 4) << 2);
  const int col0 = (bn << 7) + (wc << 6) + (lane & 15);
#pragma unroll
  for (int m = 0; m < 4; ++m)
#pragma unroll
    for (int n = 0; n < 4; ++n)
#pragma unroll
      for (int j = 0; j < 4; ++j) {
        size_t idx = (size_t)(row0 + m * 16 + j) * N + col0 + n * 16;
        if (OUT_BF16) ((u16*)Cout)[idx] = f2bf(acc[m][n][j]);
        else          ((float*)Cout)[idx] = acc[m][n][j];
      }
}

// ---------------- RMSNorm + RoPE for q and k ----------------
__global__ __launch_bounds__(256)
void normrope_kernel(const u16* __restrict__ qkv, const float* __restrict__ qw,
                     const float* __restrict__ kw, const float* __restrict__ ct,
                     const float* __restrict__ st, u16* __restrict__ q_r,
                     u16* __restrict__ k_r) {
  const int lane = threadIdx.x & 63;
  const int row = blockIdx.x * 4 + (threadIdx.x >> 6);
  const int nq = B_N * S_N * H_N;
  const u16* src; u16* dst; const float* w;
  int s;
  if (row < nq) {
    int h = row & 7; int bs = row >> 3; s = bs & (S_N - 1); int b = bs >> 11;
    src = qkv + (size_t)(b * S_N + s) * QKVW + h * 256;
    dst = q_r + ((size_t)(b * H_N + h) * S_N + s) * 256;
    w = qw;
  } else {
    int r2 = row - nq;
    int h = r2 & 1; int bs = r2 >> 1; s = bs & (S_N - 1); int b = bs >> 11;
    src = qkv + (size_t)(b * S_N + s) * QKVW + 4096 + h * 256;
    dst = k_r + ((size_t)(b * HKV_N + h) * S_N + s) * 256;
    w = kw;
  }
  u16x4 xv = *reinterpret_cast<const u16x4*>(src + lane * 4);
  float x0 = bf2f(xv.x), x1 = bf2f(xv.y), x2 = bf2f(xv.z), x3 = bf2f(xv.w);
  float ss = x0 * x0 + x1 * x1 + x2 * x2 + x3 * x3;
#pragma unroll
  for (int off = 1; off < 64; off <<= 1) ss += __shfl_xor(ss, off);
  float rinv = rsqrtf(ss * (1.0f / 256.0f) + 1e-6f);
  float4 wv = *reinterpret_cast<const float4*>(w + lane * 4);
  float y[4] = { x0 * rinv * wv.x, x1 * rinv * wv.y, x2 * rinv * wv.z, x3 * rinv * wv.w };
  float p[4];
  p[0] = __shfl_xor(y[0], 8);
  p[1] = __shfl_xor(y[1], 8);
  p[2] = __shfl_xor(y[2], 8);
  p[3] = __shfl_xor(y[3], 8);
  if (lane < 16) {
    const float sgn = (lane < 8) ? -1.0f : 1.0f;
    const int jb = (lane * 4) & 31;
#pragma unroll
    for (int e = 0; e < 4; ++e) {
      float c = ct[(size_t)s * 32 + jb + e];
      float sn = st[(size_t)s * 32 + jb + e];
      y[e] = y[e] * c + sgn * p[e] * sn;
    }
  }
  u16x4 ov;
  ov.x = f2bf(y[0]); ov.y = f2bf(y[1]); ov.z = f2bf(y[2]); ov.w = f2bf(y[3]);
  *reinterpret_cast<u16x4*>(dst + lane * 4) = ov;
}

// ---------------- V transpose ----------------
__global__ __launch_bounds__(256)
void vtrans_kernel(const u16* __restrict__ qkv, u16* __restrict__ vt) {
  const int bid = blockIdx.x;            // 512
  const int dt = bid & 3;
  const int stile = (bid >> 2) & 31;
  const int bh = bid >> 7;
  const int b = bh >> 1, kvh = bh & 1;
  __shared__ u16 tile[64][68];
  const int t = threadIdx.x;
  const u16* src = qkv + (size_t)(b * S_N + stile * 64) * QKVW + 4608 + kvh * 256 + dt * 64;
#pragma unroll
  for (int i = 0; i < 2; ++i) {
    int sl = i * 32 + (t >> 3);
    int d8 = (t & 7) * 8;
    s16x8 v = *reinterpret_cast<const s16x8*>(src + (size_t)sl * QKVW + d8);
    u16x4 lo = { (u16)v[0], (u16)v[1], (u16)v[2], (u16)v[3] };
    u16x4 hi = { (u16)v[4], (u16)v[5], (u16)v[6], (u16)v[7] };
    *reinterpret_cast<u16x4*>(&tile[sl][d8]) = lo;
    *reinterpret_cast<u16x4*>(&tile[sl][d8 + 4]) = hi;
  }
  __syncthreads();
#pragma unroll
  for (int i = 0; i < 2; ++i) {
    int dl = i * 32 + (t >> 3);
    int s8 = (t & 7) * 8;
    u16 tmp[8];
#pragma unroll
    for (int e = 0; e < 8; ++e) tmp[e] = tile[s8 + e][dl];
    u16x4 lo = { tmp[0], tmp[1], tmp[2], tmp[3] };
    u16x4 hi = { tmp[4], tmp[5], tmp[6], tmp[7] };
    u16* dstp = vt + ((size_t)(bh * 256 + dt * 64 + dl)) * S_N + stile * 64 + s8;
    *reinterpret_cast<u16x4*>(dstp) = lo;
    *reinterpret_cast<u16x4*>(dstp + 4) = hi;
  }
}

// ---------------- flash attention + silu gating (r5 structure) ----------------
// 8 waves (512 thr); wave owns 16 q rows (q-tile 128); KVBLK=64; D=256.
// Swapped QK^T + in-register softmax + packed P (v_cvt_pk) -> ds_write_b64.
__global__ __launch_bounds__(512, 2)
void attn_kernel(const u16* __restrict__ q_r, const u16* __restrict__ k_r,
                 const u16* __restrict__ vt, const u16* __restrict__ qkv,
                 u16* __restrict__ act) {
  // XCD-aware remap: 2 XCDs per (b,kvh); K/V (2MB) fits per-XCD L2.
  const int dd = blockIdx.x;             // 0..255
  const int xcd = dd & 7;
  const int idx = dd >> 3;               // 0..31
  const int combo = xcd >> 1;            // b*2+kvh
  const int within = (xcd & 1) * 32 + idx;
  const int b = combo >> 1;
  const int kvh = combo & 1;
  const int h = kvh * 4 + (within >> 4);
  const int qt = within & 15;

  const int tid = threadIdx.x;
  const int lane = tid & 63;
  const int wv = tid >> 6;               // 0..7
  const int l15 = lane & 15;
  const int l4 = lane >> 4;

  __shared__ u16 sK[2][64 * 256];        // [kv][d], swizzled 16B slots
  __shared__ u16 sVt[2][256 * 64];       // [d][kv], swizzled
  __shared__ u16 sP[8][16 * 64];         // per-wave P tile, swizzled (8B slots)

  const int q0 = qt * 128 + wv * 16;
  const u16* qb = q_r + ((size_t)(b * H_N + h) * S_N + q0) * 256;
  s16x8 qf[8];
#pragma unroll
  for (int kk = 0; kk < 8; ++kk)
    qf[kk] = *reinterpret_cast<const s16x8*>(qb + (size_t)l15 * 256 + kk * 32 + l4 * 8);

  f32x4 oacc[16] = {};
  float mrow = -1e30f;
  float lrow = 0.f;

  const u16* kbase = k_r + ((size_t)(b * HKV_N + kvh) * S_N) * 256;
  const u16* vbase = vt + ((size_t)(b * HKV_N + kvh) * 256) * S_N;

  const int krow_b = tid >> 5;           // 0..15
  const int kp = tid & 31;
  const int vrow_b = tid >> 3;           // 0..63
  const int vp = tid & 7;

  auto stageKV = [&](int buf, int step) {
    const int kv0 = step << 6;
#pragma unroll
    for (int i = 0; i < 4; ++i) {
      const int krow = i * 16 + krow_b;
      gload_lds16(kbase + (size_t)(kv0 + krow) * 256 + ((kp ^ (krow_b & 7)) << 3),
                  &sK[buf][i * 4096 + tid * 8]);
    }
#pragma unroll
    for (int i = 0; i < 4; ++i) {
      const int vrow = i * 64 + vrow_b;
      gload_lds16(vbase + (size_t)vrow * S_N + kv0 + ((vp ^ (vrow_b & 7)) << 3),
                  &sVt[buf][i * 4096 + tid * 8]);
    }
  };

  stageKV(0, 0);
  int cur = 0;
  const float scale = 0.0625f;  // 1/sqrt(256)
  const int sw = l15 & 7;
  const int swp = l15 & 14;              // even XOR for 8B P slots
  for (int step = 0; step < 32; ++step) {
    asm volatile("s_waitcnt vmcnt(0)" ::: "memory");
    __builtin_amdgcn_s_barrier();
    if (step + 1 < 32) stageKV(cur ^ 1, step + 1);
    const u16* ktile = sK[cur];
    const u16* vtile = sVt[cur];

    // swapped QK^T: sacc[g] = S^T tile; lane holds q-col = l15,
    // kv-rows = g*16 + l4*4 + j
    f32x4 sacc[4] = {};
#pragma unroll
    for (int kk = 0; kk < 8; ++kk) {
      const int slot = kk * 4 + l4;
#pragma unroll
      for (int g = 0; g < 4; ++g) {
        s16x8 kf = *reinterpret_cast<const s16x8*>(
            ktile + (g * 16 + l15) * 256 + ((slot ^ sw) << 3));
        sacc[g] = __builtin_amdgcn_mfma_f32_16x16x32_bf16(kf, qf[kk], sacc[g], 0, 0, 0);
      }
    }

    // in-register row softmax (q = l15): per-lane reduce + 2 shuffles
    float vmax = sacc[0][0];
#pragma unroll
    for (int g = 0; g < 4; ++g)
#pragma unroll
      for (int j = 0; j < 4; ++j) vmax = fmaxf(vmax, sacc[g][j]);
    vmax = fmaxf(vmax, __shfl_xor(vmax, 16));
    vmax = fmaxf(vmax, __shfl_xor(vmax, 32));
    if (__any(vmax > mrow)) {
      float mnew = fmaxf(mrow, vmax);
      float alpha = __expf((mrow - mnew) * scale);
      mrow = mnew;
      lrow *= alpha;
      float ab[4];
#pragma unroll
      for (int j = 0; j < 4; ++j) ab[j] = __shfl(alpha, l4 * 4 + j);
#pragma unroll
      for (int nf = 0; nf < 16; ++nf) {
        oacc[nf][0] *= ab[0]; oacc[nf][1] *= ab[1];
        oacc[nf][2] *= ab[2]; oacc[nf][3] *= ab[3];
      }
    }
    const float msc = mrow * scale;
    float p[16];
#pragma unroll
    for (int g = 0; g < 4; ++g)
#pragma unroll
      for (int j = 0; j < 4; ++j)
        p[g * 4 + j] = __expf(fmaf(sacc[g][j], scale, -msc));
    float r = ((p[0] + p[1]) + (p[2] + p[3])) + ((p[4] + p[5]) + (p[6] + p[7]))
            + ((p[8] + p[9]) + (p[10] + p[11])) + ((p[12] + p[13]) + (p[14] + p[15]));
    r += __shfl_xor(r, 16);
    r += __shfl_xor(r, 32);
    lrow += r;

    // P pack (bf16 pairs) -> 4 x ds_write_b64, conflict-free swizzle
    u16* pl = &sP[wv][0];
#pragma unroll
    for (int g = 0; g < 4; ++g) {
      u32 lo = pk_bf16(p[g * 4 + 0], p[g * 4 + 1]);
      u32 hi = pk_bf16(p[g * 4 + 2], p[g * 4 + 3]);
      union { u32 w[2]; u16x4 v; } u;
      u.w[0] = lo; u.w[1] = hi;
      *reinterpret_cast<u16x4*>(pl + l15 * 64 + (((g * 4 + l4) ^ swp) << 2)) = u.v;
    }
    asm volatile("s_waitcnt lgkmcnt(0)" ::: "memory");
    __builtin_amdgcn_sched_barrier(0);

    // PV: O[q][d] += P[q][kv] @ V[kv][d]
#pragma unroll
    for (int c = 0; c < 2; ++c) {
      s16x8 paf = *reinterpret_cast<const s16x8*>(
          pl + l15 * 64 + (((c * 8 + l4 * 2) ^ swp) << 2));
#pragma unroll
      for (int nf = 0; nf < 16; ++nf) {
        s16x8 vf = *reinterpret_cast<const s16x8*>(
            vtile + (nf * 16 + l15) * 64 + (((c * 4 + l4) ^ sw) << 3));
        oacc[nf] = __builtin_amdgcn_mfma_f32_16x16x32_bf16(paf, vf, oacc[nf], 0, 0, 0);
      }
    }
    cur ^= 1;
  }

  // epilogue: O/l, silu(gate), write activation for final GEMM
  float invl = 1.0f / lrow;
  float ib[4];
#pragma unroll
  for (int j = 0; j < 4; ++j) ib[j] = __shfl(invl, l4 * 4 + j);
#pragma unroll
  for (int nf = 0; nf < 16; ++nf) {
#pragma unroll
    for (int j = 0; j < 4; ++j) {
      const int srow = q0 + l4 * 4 + j;
      const int d = nf * 16 + l15;
      float o = oacc[nf][j] * ib[j];
      float g = bf2f(qkv[(size_t)(b * S_N + srow) * QKVW + 2048 + h * 256 + d]);
      float sg = g / (1.0f + __expf(-g));
      act[(size_t)(b * S_N + srow) * 2048 + h * 256 + d] = f2bf(o * sg);
    }
  }
}

extern "C" void kernel_launch(void* const* d_in, const int* in_sizes, int n_in,
                              void* d_out, int out_size, void* d_ws, size_t ws_size,
                              hipStream_t stream) {
  const float* hs  = (const float*)d_in[0];
  const int*   pos = (const int*)d_in[1];
  const float* Wq  = (const float*)d_in[2];
  const float* Wk  = (const float*)d_in[3];
  const float* Wv  = (const float*)d_in[4];
  const float* Wo  = (const float*)d_in[5];
  const float* qw  = (const float*)d_in[6];
  const float* kw  = (const float*)d_in[7];
  float* out = (float*)d_out;

  char* w8 = (char*)d_ws;
  u16* hs_bf   = (u16*)(w8);                    // 8,388,608 B
  u16* wqkv_bf = (u16*)(w8 + 8388608);          // 10,485,760
  u16* wo_bf   = (u16*)(w8 + 18874368);         // 4,194,304
  u16* qkv_raw = (u16*)(w8 + 23068672);         // 41,943,040
  u16* q_r     = (u16*)(w8 + 65011712);         // 16,777,216
  u16* k_r     = (u16*)(w8 + 81788928);         // 4,194,304
  u16* vt      = (u16*)(w8 + 85983232);         // 4,194,304
  u16* act     = (u16*)(w8 + 90177536);         // 16,777,216
  float* cost  = (float*)(w8 + 106954752);      // 262,144
  float* sint  = (float*)(w8 + 107216896);      // 262,144  -> total 107,479,040

  // fused input casts (hs, Wq, Wk, Wv, Wo -> bf16)
  cast5_kernel<<<2048, 256, 0, stream>>>(hs, Wq, Wk, Wv, Wo, hs_bf, wqkv_bf, wo_bf);

  trig_kernel<<<(S_N * 32) / 256, 256, 0, stream>>>(pos, cost, sint);

  // QKV+gate projection: M=4096, N=5120, K=1024 -> qkv_raw bf16
  // grid 1280 = 8 XCDs x (32 bm x 5 bn)
  gemm_bt_kernel<1><<<1280, 256, 0, stream>>>(hs_bf, wqkv_bf, (void*)qkv_raw,
                                              4096, 5120, 1024, 5);

  // RMSNorm + RoPE (q,k); V transpose
  normrope_kernel<<<(B_N * S_N * (H_N + HKV_N)) / 4, 256, 0, stream>>>(
      qkv_raw, qw, kw, cost, sint, q_r, k_r);
  vtrans_kernel<<<512, 256, 0, stream>>>(qkv_raw, vt);

  // attention + gating -> act bf16 (grid 256 = 1 block/CU, 8 waves)
  attn_kernel<<<256, 512, 0, stream>>>(q_r, k_r, vt, qkv_raw, act);

  // output projection: M=4096, N=1024, K=2048 -> d_out fp32
  // grid 256 = 8 XCDs x (32 bm x 1 bn)
  gemm_bt_kernel<0><<<256, 256, 0, stream>>>(act, wo_bf, (void*)out,
                                             4096, 1024, 2048, 1);
}